// Round 2
// baseline (8569.646 us; speedup 1.0000x reference)
//
#include <hip/hip_runtime.h>
#include <hip/hip_bf16.h>

// Problem constants (fixed shapes per reference setup_inputs; n_step = 200).
#define MM 64        // batch
#define NN 4096      // neurons
#define KK 4096
#define NSTEP 200

#define MT 32        // m-tile per block (2 m-halves)
#define NT 32        // n-tile per block (128 strips)  -> 256 blocks
#define BK 64        // k-chunk staged in LDS
#define LDP (BK + 8) // LDS pitch (bf16 elems); 144B rows keep 16B alignment

typedef __bf16 bf16x8 __attribute__((ext_vector_type(8)));
typedef float  f32x4  __attribute__((ext_vector_type(4)));

static __device__ __forceinline__ unsigned short f2bf(float f) {
    __hip_bfloat16 h = __float2bfloat16(f);
    return __builtin_bit_cast(unsigned short, h);
}
static __device__ __forceinline__ float bf2f(unsigned short u) {
    __hip_bfloat16 h = __builtin_bit_cast(__hip_bfloat16, u);
    return __bfloat162float(h);
}

// ---------------------------------------------------------------------------
// Prologue 1: s = 0.5*(W[n][k]+W[k][n]), diag zero; Whi = bf16(s),
// Wlo = bf16(s - Whi).  64x64 tiles, LDS transpose.
// ---------------------------------------------------------------------------
__global__ __launch_bounds__(256) void symm_kernel(const float* __restrict__ W,
                                                   unsigned short* __restrict__ Whi,
                                                   unsigned short* __restrict__ Wlo) {
    __shared__ float T[64][65];
    const int tid = threadIdx.x;
    const int r0 = blockIdx.y * 64, c0 = blockIdx.x * 64;
#pragma unroll
    for (int i = 0; i < 4; ++i) {
        int lin = tid + i * 256;
        int cc  = lin >> 4;
        int r4  = (lin & 15) * 4;
        float4 v = *(const float4*)&W[(size_t)(c0 + cc) * NN + r0 + r4];
        T[cc][r4 + 0] = v.x; T[cc][r4 + 1] = v.y;
        T[cc][r4 + 2] = v.z; T[cc][r4 + 3] = v.w;
    }
    __syncthreads();
#pragma unroll
    for (int i = 0; i < 4; ++i) {
        int lin = tid + i * 256;
        int rr  = lin >> 4;
        int c4  = (lin & 15) * 4;
        float4 v = *(const float4*)&W[(size_t)(r0 + rr) * NN + c0 + c4];
        float d[4] = {v.x, v.y, v.z, v.w};
        ushort4 ohi, olo;
        unsigned short* ph = (unsigned short*)&ohi;
        unsigned short* pl = (unsigned short*)&olo;
#pragma unroll
        for (int j = 0; j < 4; ++j) {
            float s = 0.5f * (d[j] + T[c4 + j][rr]);
            if (r0 + rr == c0 + c4 + j) s = 0.0f;
            unsigned short hi = f2bf(s);
            ph[j] = hi;
            pl[j] = f2bf(s - bf2f(hi));
        }
        size_t o = (size_t)(r0 + rr) * NN + c0 + c4;
        *(ushort4*)&Whi[o] = ohi;
        *(ushort4*)&Wlo[o] = olo;
    }
}

// ---------------------------------------------------------------------------
// Prologue 2: x0 = (1/beta)*log(g/(1-g)); g -> (ghi, glo)
// ---------------------------------------------------------------------------
__global__ __launch_bounds__(256) void init_kernel(const float* __restrict__ g_in,
                                                   const float* __restrict__ beta,
                                                   float* __restrict__ x,
                                                   unsigned short* __restrict__ ghi,
                                                   unsigned short* __restrict__ glo) {
    int idx = blockIdx.x * 256 + threadIdx.x;
    int n = idx & (NN - 1);
    float g = g_in[idx];
    x[idx] = logf(g / (1.0f - g)) / beta[n];
    unsigned short hi = f2bf(g);
    ghi[idx] = hi;
    glo[idx] = f2bf(g - bf2f(hi));
}

// ---------------------------------------------------------------------------
// Prologue 3: max_x = 50 / max(beta)
// ---------------------------------------------------------------------------
__global__ __launch_bounds__(256) void maxx_kernel(const float* __restrict__ beta,
                                                   float* __restrict__ out) {
    __shared__ float red[256];
    float m = -1e30f;
    for (int i = threadIdx.x; i < NN; i += 256) m = fmaxf(m, beta[i]);
    red[threadIdx.x] = m;
    __syncthreads();
    for (int s = 128; s > 0; s >>= 1) {
        if (threadIdx.x < s) red[threadIdx.x] = fmaxf(red[threadIdx.x], red[threadIdx.x + s]);
        __syncthreads();
    }
    if (threadIdx.x == 0) out[0] = 50.0f / red[0];
}

// ---------------------------------------------------------------------------
// One fused step, split-precision:
//   pre = ghi@Whi + glo@Whi + ghi@Wlo + b    (~fp32-accurate)
//   x   = clip(alpha*pre + (1-alpha)*x, -mx, mx);  g = sigmoid(beta*x)
// Grid 256 blocks: n-strip s=0..127 (NT=32 cols), m-half 0/1 (MT=32 rows).
// Blocks bx and bx+8 share a W strip (same XCD under round-robin dispatch).
// 4 waves/block, each computes one 16x16 output tile via mfma 16x16x32 bf16.
// A[m=lane&15][k=quad*8+j], C/D: col=lane&15, row=quad*4+reg (m89 mapping).
// ---------------------------------------------------------------------------
__global__ __launch_bounds__(256) void step_kernel(
    const unsigned short* __restrict__ ghi_in,
    const unsigned short* __restrict__ glo_in,
    unsigned short* __restrict__ ghi_out,
    unsigned short* __restrict__ glo_out,
    float* __restrict__ x,                    // [64][4096] f32, in-place
    const unsigned short* __restrict__ Whi,   // [4096][4096] bf16 (symmetric)
    const unsigned short* __restrict__ Wlo,
    const float* __restrict__ bvec,
    const float* __restrict__ beta,
    const float* __restrict__ tau,
    const float* __restrict__ dt_ptr,
    const float* __restrict__ maxx_ptr,
    float* __restrict__ gout_f32)             // non-null on last step only
{
    __shared__ __align__(16) unsigned short sGhi[MT][LDP];
    __shared__ __align__(16) unsigned short sGlo[MT][LDP];
    __shared__ __align__(16) unsigned short sWhi[NT][LDP];
    __shared__ __align__(16) unsigned short sWlo[NT][LDP];

    const int tid  = threadIdx.x;
    const int wave = tid >> 6;
    const int lane = tid & 63;
    const int q    = lane >> 4;
    const int l16  = lane & 15;

    const int bx    = blockIdx.x;
    const int strip = (bx >> 4) * 8 + (bx & 7);   // 0..127
    const int m0    = ((bx >> 3) & 1) * MT;       // 0 or 32
    const int n0    = strip * NT;

    const int wm = (wave >> 1) * 16;   // wave's m offset in tile
    const int wn = (wave & 1) * 16;    // wave's n offset in tile

    f32x4 acc = {0.0f, 0.0f, 0.0f, 0.0f};

    const int r  = tid >> 3;          // 0..31 staging row
    const int c8 = (tid & 7) * 8;     // staging col (8 bf16 = 16B)

    const size_t gA = (size_t)(m0 + r) * NN + c8;
    const size_t wA = (size_t)(n0 + r) * NN + c8;

    for (int k0 = 0; k0 < KK; k0 += BK) {
        *(uint4*)&sGhi[r][c8] = *(const uint4*)&ghi_in[gA + k0];
        *(uint4*)&sGlo[r][c8] = *(const uint4*)&glo_in[gA + k0];
        *(uint4*)&sWhi[r][c8] = *(const uint4*)&Whi[wA + k0];
        *(uint4*)&sWlo[r][c8] = *(const uint4*)&Wlo[wA + k0];
        __syncthreads();
#pragma unroll
        for (int kk = 0; kk < BK; kk += 32) {
            bf16x8 ahi = *reinterpret_cast<bf16x8*>(&sGhi[wm + l16][kk + q * 8]);
            bf16x8 alo = *reinterpret_cast<bf16x8*>(&sGlo[wm + l16][kk + q * 8]);
            bf16x8 bhi = *reinterpret_cast<bf16x8*>(&sWhi[wn + l16][kk + q * 8]);
            bf16x8 blo = *reinterpret_cast<bf16x8*>(&sWlo[wn + l16][kk + q * 8]);
            acc = __builtin_amdgcn_mfma_f32_16x16x32_bf16(ahi, bhi, acc, 0, 0, 0);
            acc = __builtin_amdgcn_mfma_f32_16x16x32_bf16(alo, bhi, acc, 0, 0, 0);
            acc = __builtin_amdgcn_mfma_f32_16x16x32_bf16(ahi, blo, acc, 0, 0, 0);
        }
        __syncthreads();
    }

    // epilogue
    const float dt = *dt_ptr;
    const float mx = *maxx_ptr;
    const int col = n0 + wn + l16;
    const float bn = bvec[col];
    const float be = beta[col];
    const float al = dt / tau[col];
#pragma unroll
    for (int rg = 0; rg < 4; ++rg) {
        const int row = m0 + wm + q * 4 + rg;
        const size_t off = (size_t)row * NN + col;
        float pre = acc[rg] + bn;
        float xo  = x[off];
        float xn  = al * pre + (1.0f - al) * xo;
        xn = fminf(fmaxf(xn, -mx), mx);
        float g = 1.0f / (1.0f + expf(-be * xn));
        x[off] = xn;
        unsigned short hi = f2bf(g);
        ghi_out[off] = hi;
        glo_out[off] = f2bf(g - bf2f(hi));
        if (gout_f32) gout_f32[off] = g;
    }
}

// ---------------------------------------------------------------------------
extern "C" void kernel_launch(void* const* d_in, const int* in_sizes, int n_in,
                              void* d_out, int out_size, void* d_ws, size_t ws_size,
                              hipStream_t stream) {
    const float* state_g = (const float*)d_in[0];
    const float* W       = (const float*)d_in[1];
    const float* b       = (const float*)d_in[2];
    const float* beta    = (const float*)d_in[3];
    const float* tau     = (const float*)d_in[4];
    const float* dt      = (const float*)d_in[5];
    float* out = (float*)d_out;

    char* ws = (char*)d_ws;
    const size_t WH = (size_t)KK * NN * 2;   // 32 MB each
    const size_t XB = (size_t)MM * NN * 4;   // 1 MB
    const size_t GB = (size_t)MM * NN * 2;   // 512 KB each
    unsigned short* Whi = (unsigned short*)ws;
    unsigned short* Wlo = (unsigned short*)(ws + WH);
    float*          x   = (float*)(ws + 2 * WH);
    unsigned short* g0h = (unsigned short*)(ws + 2 * WH + XB);
    unsigned short* g0l = (unsigned short*)(ws + 2 * WH + XB + GB);
    unsigned short* g1h = (unsigned short*)(ws + 2 * WH + XB + 2 * GB);
    unsigned short* g1l = (unsigned short*)(ws + 2 * WH + XB + 3 * GB);
    float*          mxp = (float*)(ws + 2 * WH + XB + 4 * GB);

    symm_kernel<<<dim3(64, 64), 256, 0, stream>>>(W, Whi, Wlo);
    init_kernel<<<(MM * NN) / 256, 256, 0, stream>>>(state_g, beta, x, g0h, g0l);
    maxx_kernel<<<1, 256, 0, stream>>>(beta, mxp);

    unsigned short *gih = g0h, *gil = g0l, *goh = g1h, *gol = g1l;
    for (int s = 0; s < NSTEP; ++s) {
        float* of = (s == NSTEP - 1) ? out : nullptr;
        step_kernel<<<256, 256, 0, stream>>>(gih, gil, goh, gol, x, Whi, Wlo,
                                             b, beta, tau, dt, mxp, of);
        unsigned short* t;
        t = gih; gih = goh; goh = t;
        t = gil; gil = gol; gol = t;
    }
}

// Round 3
// 4778.881 us; speedup vs baseline: 1.7932x; 1.7932x over previous
//
#include <hip/hip_runtime.h>
#include <hip/hip_bf16.h>

// Problem constants (fixed shapes per reference setup_inputs; n_step = 200).
#define MM 64        // batch
#define NN 4096      // neurons
#define KK 4096
#define NSTEP 200

typedef __bf16 bf16x8 __attribute__((ext_vector_type(8)));
typedef float  f32x4  __attribute__((ext_vector_type(4)));

static __device__ __forceinline__ unsigned short f2bf(float f) {
    __hip_bfloat16 h = __float2bfloat16(f);
    return __builtin_bit_cast(unsigned short, h);
}
static __device__ __forceinline__ float bf2f(unsigned short u) {
    __hip_bfloat16 h = __builtin_bit_cast(__hip_bfloat16, u);
    return __bfloat162float(h);
}

// Fragment-order layouts (16x16x32 bf16 MFMA, m89-verified lane mapping
// frag[lane=q*16+l16][j] = Mat[row=base+l16][col=kbase+q*8+j]):
//   Wfrag: [strip 128][nt 2][kc 128][lane 64][8]   (rows of symmetric W = B cols)
//   gfrag: [ms 4][kc 128][lane 64][8]
// Both give perfectly coalesced 16B/lane K-loop loads; no LDS staging needed.

// ---------------------------------------------------------------------------
// Prologue 1: s = 0.5*(W[n][k]+W[k][n]), diag zero; split s -> (hi,lo) bf16
// and scatter into W-fragment order. 64x64 tiles, LDS transpose.
// ---------------------------------------------------------------------------
__global__ __launch_bounds__(256) void symm_kernel(const float* __restrict__ W,
                                                   unsigned short* __restrict__ Wfh,
                                                   unsigned short* __restrict__ Wfl) {
    __shared__ float T[64][65];
    const int tid = threadIdx.x;
    const int r0 = blockIdx.y * 64, c0 = blockIdx.x * 64;
#pragma unroll
    for (int i = 0; i < 4; ++i) {
        int lin = tid + i * 256;
        int cc  = lin >> 4;
        int r4  = (lin & 15) * 4;
        float4 v = *(const float4*)&W[(size_t)(c0 + cc) * NN + r0 + r4];
        T[cc][r4 + 0] = v.x; T[cc][r4 + 1] = v.y;
        T[cc][r4 + 2] = v.z; T[cc][r4 + 3] = v.w;
    }
    __syncthreads();
#pragma unroll
    for (int i = 0; i < 4; ++i) {
        int lin = tid + i * 256;
        int rr  = lin >> 4;
        int c4  = (lin & 15) * 4;
        float4 v = *(const float4*)&W[(size_t)(r0 + rr) * NN + c0 + c4];
        float d[4] = {v.x, v.y, v.z, v.w};
        ushort4 ohi, olo;
        unsigned short* ph = (unsigned short*)&ohi;
        unsigned short* pl = (unsigned short*)&olo;
#pragma unroll
        for (int j = 0; j < 4; ++j) {
            float s = 0.5f * (d[j] + T[c4 + j][rr]);
            if (r0 + rr == c0 + c4 + j) s = 0.0f;
            unsigned short hi = f2bf(s);
            ph[j] = hi;
            pl[j] = f2bf(s - bf2f(hi));
        }
        const int n  = r0 + rr;          // W row (= B column, symmetric)
        const int k0 = c0 + c4;          // 4-aligned -> j0 in {0,4}
        const int s_ = n >> 5, t_ = (n >> 4) & 1, ln = n & 15;
        const int kc = k0 >> 5, qk = (k0 & 31) >> 3, j0 = k0 & 7;
        size_t off = (((size_t)(s_ * 2 + t_) * 128 + kc) * 64 + qk * 16 + ln) * 8 + j0;
        *(ushort4*)&Wfh[off] = ohi;      // 8B aligned
        *(ushort4*)&Wfl[off] = olo;
    }
}

// ---------------------------------------------------------------------------
// Prologue 2: x0 = (1/beta)*log(g/(1-g)); g -> (hi,lo) scattered to gfrag order
// ---------------------------------------------------------------------------
__global__ __launch_bounds__(256) void init_kernel(const float* __restrict__ g_in,
                                                   const float* __restrict__ beta,
                                                   float* __restrict__ x,
                                                   unsigned short* __restrict__ gfh,
                                                   unsigned short* __restrict__ gfl) {
    int idx = blockIdx.x * 256 + threadIdx.x;   // 0 .. 64*4096-1
    int r = idx >> 12, c = idx & (NN - 1);
    float g = g_in[idx];
    x[idx] = logf(g / (1.0f - g)) / beta[c];
    unsigned short hi = f2bf(g);
    unsigned short lo = f2bf(g - bf2f(hi));
    const int ms = r >> 4, l16 = r & 15;
    const int kc = c >> 5, qk = (c & 31) >> 3, j = c & 7;
    size_t off = (((size_t)ms * 128 + kc) * 64 + qk * 16 + l16) * 8 + j;
    gfh[off] = hi;
    gfl[off] = lo;
}

// ---------------------------------------------------------------------------
// Prologue 3: max_x = 50 / max(beta)
// ---------------------------------------------------------------------------
__global__ __launch_bounds__(256) void maxx_kernel(const float* __restrict__ beta,
                                                   float* __restrict__ out) {
    __shared__ float red[256];
    float m = -1e30f;
    for (int i = threadIdx.x; i < NN; i += 256) m = fmaxf(m, beta[i]);
    red[threadIdx.x] = m;
    __syncthreads();
    for (int s = 128; s > 0; s >>= 1) {
        if (threadIdx.x < s) red[threadIdx.x] = fmaxf(red[threadIdx.x], red[threadIdx.x + s]);
        __syncthreads();
    }
    if (threadIdx.x == 0) out[0] = 50.0f / red[0];
}

// ---------------------------------------------------------------------------
// One fused step. 256 blocks x 512 threads (8 waves).
// Block: 32x32 output tile (mhalf x strip). Wave w: K-slice [w*512,(w+1)*512),
// computing the full 32x32 as 2x2 MFMA tiles: per 32-K chunk, 8 coalesced
// global frag loads -> 12 MFMAs. No LDS / no barriers in the K-loop.
// After: waves 1-7 dump acc to LDS, one barrier, wave 0 reduces + fused
// epilogue + re-fragments g for the next step via a 5 KB LDS transpose.
// ---------------------------------------------------------------------------
__global__ __launch_bounds__(512) void step_kernel(
    const unsigned short* __restrict__ gfh_in,
    const unsigned short* __restrict__ gfl_in,
    unsigned short* __restrict__ gfh_out,
    unsigned short* __restrict__ gfl_out,
    float* __restrict__ x,                    // [64][4096] f32, in-place
    const unsigned short* __restrict__ Wfh,   // frag-ordered, 32 MB
    const unsigned short* __restrict__ Wfl,
    const float* __restrict__ bvec,
    const float* __restrict__ beta,
    const float* __restrict__ tau,
    const float* __restrict__ dt_ptr,
    const float* __restrict__ maxx_ptr,
    float* __restrict__ gout_f32)             // non-null on last step only
{
    __shared__ float red[7][4][16][17];            // 30.5 KB
    __shared__ unsigned short gt[2][2][16][40];    // 5 KB  [hi/lo][mt][row][col+pad]

    const int tid  = threadIdx.x;
    const int w    = tid >> 6;       // wave = K-slice 0..7
    const int lane = tid & 63;
    const int q    = lane >> 4;
    const int l16  = lane & 15;

    const int bx    = blockIdx.x;
    const int strip = (bx >> 4) * 8 + (bx & 7);   // 0..127 (XCD swizzle)
    const int mhalf = (bx >> 3) & 1;
    const int m0    = mhalf * 32;

    f32x4 acc[2][2] = {{{0,0,0,0},{0,0,0,0}},{{0,0,0,0},{0,0,0,0}}};

    const int kc0 = w * 16;
    const size_t a0 = (((size_t)(mhalf * 2 + 0) * 128 + kc0) * 64 + lane) * 8;
    const size_t a1 = (((size_t)(mhalf * 2 + 1) * 128 + kc0) * 64 + lane) * 8;
    const size_t b0 = (((size_t)(strip * 2 + 0) * 128 + kc0) * 64 + lane) * 8;
    const size_t b1 = (((size_t)(strip * 2 + 1) * 128 + kc0) * 64 + lane) * 8;

#pragma unroll 4
    for (int it = 0; it < 16; ++it) {
        const size_t d = (size_t)it * 512;        // 64 lanes * 8 ushorts per kc
        bf16x8 ah0 = *(const bf16x8*)&gfh_in[a0 + d];
        bf16x8 ah1 = *(const bf16x8*)&gfh_in[a1 + d];
        bf16x8 al0 = *(const bf16x8*)&gfl_in[a0 + d];
        bf16x8 al1 = *(const bf16x8*)&gfl_in[a1 + d];
        bf16x8 bh0 = *(const bf16x8*)&Wfh[b0 + d];
        bf16x8 bh1 = *(const bf16x8*)&Wfh[b1 + d];
        bf16x8 bl0 = *(const bf16x8*)&Wfl[b0 + d];
        bf16x8 bl1 = *(const bf16x8*)&Wfl[b1 + d];
        acc[0][0] = __builtin_amdgcn_mfma_f32_16x16x32_bf16(ah0, bh0, acc[0][0], 0, 0, 0);
        acc[0][0] = __builtin_amdgcn_mfma_f32_16x16x32_bf16(al0, bh0, acc[0][0], 0, 0, 0);
        acc[0][0] = __builtin_amdgcn_mfma_f32_16x16x32_bf16(ah0, bl0, acc[0][0], 0, 0, 0);
        acc[0][1] = __builtin_amdgcn_mfma_f32_16x16x32_bf16(ah0, bh1, acc[0][1], 0, 0, 0);
        acc[0][1] = __builtin_amdgcn_mfma_f32_16x16x32_bf16(al0, bh1, acc[0][1], 0, 0, 0);
        acc[0][1] = __builtin_amdgcn_mfma_f32_16x16x32_bf16(ah0, bl1, acc[0][1], 0, 0, 0);
        acc[1][0] = __builtin_amdgcn_mfma_f32_16x16x32_bf16(ah1, bh0, acc[1][0], 0, 0, 0);
        acc[1][0] = __builtin_amdgcn_mfma_f32_16x16x32_bf16(al1, bh0, acc[1][0], 0, 0, 0);
        acc[1][0] = __builtin_amdgcn_mfma_f32_16x16x32_bf16(ah1, bl0, acc[1][0], 0, 0, 0);
        acc[1][1] = __builtin_amdgcn_mfma_f32_16x16x32_bf16(ah1, bh1, acc[1][1], 0, 0, 0);
        acc[1][1] = __builtin_amdgcn_mfma_f32_16x16x32_bf16(al1, bh1, acc[1][1], 0, 0, 0);
        acc[1][1] = __builtin_amdgcn_mfma_f32_16x16x32_bf16(ah1, bl1, acc[1][1], 0, 0, 0);
    }

    if (w > 0) {
#pragma unroll
        for (int mt = 0; mt < 2; ++mt)
#pragma unroll
            for (int nt = 0; nt < 2; ++nt)
#pragma unroll
                for (int rg = 0; rg < 4; ++rg)
                    red[w - 1][mt * 2 + nt][q * 4 + rg][l16] = acc[mt][nt][rg];
    }
    __syncthreads();
    if (w != 0) return;

#pragma unroll
    for (int t = 0; t < 7; ++t)
#pragma unroll
        for (int mt = 0; mt < 2; ++mt)
#pragma unroll
            for (int nt = 0; nt < 2; ++nt)
#pragma unroll
                for (int rg = 0; rg < 4; ++rg)
                    acc[mt][nt][rg] += red[t][mt * 2 + nt][q * 4 + rg][l16];

    // fused epilogue (wave 0 only; 16 outputs/lane)
    const float dt = *dt_ptr;
    const float mx = *maxx_ptr;
    int   coln[2];
    float bn[2], be[2], al[2];
#pragma unroll
    for (int nt = 0; nt < 2; ++nt) {
        coln[nt] = strip * 32 + nt * 16 + l16;
        bn[nt] = bvec[coln[nt]];
        be[nt] = beta[coln[nt]];
        al[nt] = dt / tau[coln[nt]];
    }
#pragma unroll
    for (int mt = 0; mt < 2; ++mt)
#pragma unroll
        for (int nt = 0; nt < 2; ++nt)
#pragma unroll
            for (int rg = 0; rg < 4; ++rg) {
                const int row = m0 + mt * 16 + q * 4 + rg;
                const size_t off = (size_t)row * NN + coln[nt];
                float pre = acc[mt][nt][rg] + bn[nt];
                float xo  = x[off];
                float xn  = al[nt] * pre + (1.0f - al[nt]) * xo;
                xn = fminf(fmaxf(xn, -mx), mx);
                float g = 1.0f / (1.0f + expf(-be[nt] * xn));
                x[off] = xn;
                unsigned short hi = f2bf(g);
                gt[0][mt][q * 4 + rg][nt * 16 + l16] = hi;
                gt[1][mt][q * 4 + rg][nt * 16 + l16] = f2bf(g - bf2f(hi));
                if (gout_f32) gout_f32[off] = g;
            }

    // re-fragment g for the next step (kc == strip for this block's columns)
#pragma unroll
    for (int mt = 0; mt < 2; ++mt) {
        bf16x8 vh = *(const bf16x8*)&gt[0][mt][l16][q * 8];
        bf16x8 vl = *(const bf16x8*)&gt[1][mt][l16][q * 8];
        const size_t o = (((size_t)(mhalf * 2 + mt) * 128 + strip) * 64 + lane) * 8;
        *(bf16x8*)&gfh_out[o] = vh;
        *(bf16x8*)&gfl_out[o] = vl;
    }
}

// ---------------------------------------------------------------------------
extern "C" void kernel_launch(void* const* d_in, const int* in_sizes, int n_in,
                              void* d_out, int out_size, void* d_ws, size_t ws_size,
                              hipStream_t stream) {
    const float* state_g = (const float*)d_in[0];
    const float* W       = (const float*)d_in[1];
    const float* b       = (const float*)d_in[2];
    const float* beta    = (const float*)d_in[3];
    const float* tau     = (const float*)d_in[4];
    const float* dt      = (const float*)d_in[5];
    float* out = (float*)d_out;

    char* ws = (char*)d_ws;
    const size_t WH = (size_t)KK * NN * 2;   // 32 MB per W-frag array
    const size_t XB = (size_t)MM * NN * 4;   // 1 MB
    const size_t GB = (size_t)MM * NN * 2;   // 512 KB per g-frag array
    unsigned short* Wfh = (unsigned short*)ws;
    unsigned short* Wfl = (unsigned short*)(ws + WH);
    float*          x   = (float*)(ws + 2 * WH);
    unsigned short* g0h = (unsigned short*)(ws + 2 * WH + XB);
    unsigned short* g0l = (unsigned short*)(ws + 2 * WH + XB + GB);
    unsigned short* g1h = (unsigned short*)(ws + 2 * WH + XB + 2 * GB);
    unsigned short* g1l = (unsigned short*)(ws + 2 * WH + XB + 3 * GB);
    float*          mxp = (float*)(ws + 2 * WH + XB + 4 * GB);

    symm_kernel<<<dim3(64, 64), 256, 0, stream>>>(W, Wfh, Wfl);
    init_kernel<<<(MM * NN) / 256, 256, 0, stream>>>(state_g, beta, x, g0h, g0l);
    maxx_kernel<<<1, 256, 0, stream>>>(beta, mxp);

    unsigned short *gih = g0h, *gil = g0l, *goh = g1h, *gol = g1l;
    for (int s = 0; s < NSTEP; ++s) {
        float* of = (s == NSTEP - 1) ? out : nullptr;
        step_kernel<<<256, 512, 0, stream>>>(gih, gil, goh, gol, x, Wfh, Wfl,
                                             b, beta, tau, dt, mxp, of);
        unsigned short* t;
        t = gih; gih = goh; goh = t;
        t = gil; gil = gol; gol = t;
    }
}

// Round 5
// 4219.366 us; speedup vs baseline: 2.0310x; 1.1326x over previous
//
#include <hip/hip_runtime.h>
#include <hip/hip_bf16.h>

// Problem constants (fixed shapes per reference setup_inputs; n_step = 200).
#define MM 64
#define NN 4096
#define KK 4096
#define NSTEP 200
#define NSLICE 8     // K-slices per strip (gemm grid = 32 strips x 8 slices)
#define NSTRIP 32    // 128-column strips
#define NPART 16     // partial slices = NSLICE * 2 (per-wave kh split)

typedef __bf16 bf16x8 __attribute__((ext_vector_type(8)));
typedef float  f32x4  __attribute__((ext_vector_type(4)));

static __device__ __forceinline__ unsigned short f2bf(float f) {
    __hip_bfloat16 h = __float2bfloat16(f);
    return __builtin_bit_cast(unsigned short, h);
}
static __device__ __forceinline__ float bf2f(unsigned short u) {
    __hip_bfloat16 h = __builtin_bit_cast(__hip_bfloat16, u);
    return __bfloat162float(h);
}

// Fragment layouts (mfma_f32_16x16x32_bf16, m89 mapping:
//   frag[lane=q*16+l16][j] = Mat[row16=l16][k=q*8+j]):
// A (g):  addr(m,kg) = ((kc*4 + (m>>4))*64 + q*16 + (m&15))*8 + j
//         with kc=kg>>5, q=(kg&31)>>3, j=kg&7                       (1 MB hi+lo)
// B (W):  addr(n,kg) = (((s*8 + ns)*128 + kc)*64 + q*16 + (n&15))*8 + j
//         with s=n>>7, ns=(n>>4)&7                                  (32 MB each)
// Partials P[part 16][s 32][row 64][col 128] fp32 (16 MB); part = k*2 + kh.

// ---------------------------------------------------------------------------
// Prologue 1: s = 0.5*(W[n][k]+W[k][n]), diag zero; (hi,lo) bf16 split,
// scattered into B-fragment order. 64x64 tiles, LDS transpose.
// ---------------------------------------------------------------------------
__global__ __launch_bounds__(256) void symm_kernel(const float* __restrict__ W,
                                                   unsigned short* __restrict__ Wfh,
                                                   unsigned short* __restrict__ Wfl) {
    __shared__ float T[64][65];
    const int tid = threadIdx.x;
    const int r0 = blockIdx.y * 64, c0 = blockIdx.x * 64;
#pragma unroll
    for (int i = 0; i < 4; ++i) {
        int lin = tid + i * 256;
        int cc  = lin >> 4;
        int r4  = (lin & 15) * 4;
        float4 v = *(const float4*)&W[(size_t)(c0 + cc) * NN + r0 + r4];
        T[cc][r4 + 0] = v.x; T[cc][r4 + 1] = v.y;
        T[cc][r4 + 2] = v.z; T[cc][r4 + 3] = v.w;
    }
    __syncthreads();
#pragma unroll
    for (int i = 0; i < 4; ++i) {
        int lin = tid + i * 256;
        int rr  = lin >> 4;
        int c4  = (lin & 15) * 4;
        float4 v = *(const float4*)&W[(size_t)(r0 + rr) * NN + c0 + c4];
        float d[4] = {v.x, v.y, v.z, v.w};
        ushort4 ohi, olo;
        unsigned short* ph = (unsigned short*)&ohi;
        unsigned short* pl = (unsigned short*)&olo;
#pragma unroll
        for (int j = 0; j < 4; ++j) {
            float sv = 0.5f * (d[j] + T[c4 + j][rr]);
            if (r0 + rr == c0 + c4 + j) sv = 0.0f;
            unsigned short hi = f2bf(sv);
            ph[j] = hi;
            pl[j] = f2bf(sv - bf2f(hi));
        }
        const int n  = r0 + rr;            // W row == output column
        const int kg = c0 + c4;            // 4-aligned
        const int s_ = n >> 7, ns = (n >> 4) & 7, ln = n & 15;
        const int kc = kg >> 5, q = (kg & 31) >> 3, j0 = kg & 7;
        size_t off = ((((size_t)(s_ * 8 + ns) * 128 + kc) * 64 + q * 16 + ln)) * 8 + j0;
        *(ushort4*)&Wfh[off] = ohi;        // 8B-aligned
        *(ushort4*)&Wfl[off] = olo;
    }
}

// ---------------------------------------------------------------------------
// Prologue 2: x0 = (1/beta)*log(g/(1-g)) (plain layout); g -> A-frag (hi,lo)
// ---------------------------------------------------------------------------
__global__ __launch_bounds__(256) void init_kernel(const float* __restrict__ g_in,
                                                   const float* __restrict__ beta,
                                                   float* __restrict__ x,
                                                   unsigned short* __restrict__ gfh,
                                                   unsigned short* __restrict__ gfl) {
    int idx = blockIdx.x * 256 + threadIdx.x;
    int r = idx >> 12, c = idx & (NN - 1);
    float g = g_in[idx];
    x[idx] = logf(g / (1.0f - g)) / beta[c];
    unsigned short hi = f2bf(g);
    unsigned short lo = f2bf(g - bf2f(hi));
    size_t off = (((size_t)(c >> 5) * 4 + (r >> 4)) * 64 + ((c & 31) >> 3) * 16 + (r & 15)) * 8 + (c & 7);
    gfh[off] = hi;
    gfl[off] = lo;
}

// ---------------------------------------------------------------------------
// Prologue 3: max_x = 50 / max(beta)
// ---------------------------------------------------------------------------
__global__ __launch_bounds__(256) void maxx_kernel(const float* __restrict__ beta,
                                                   float* __restrict__ out) {
    __shared__ float red[256];
    float m = -1e30f;
    for (int i = threadIdx.x; i < NN; i += 256) m = fmaxf(m, beta[i]);
    red[threadIdx.x] = m;
    __syncthreads();
    for (int s = 128; s > 0; s >>= 1) {
        if (threadIdx.x < s) red[threadIdx.x] = fmaxf(red[threadIdx.x], red[threadIdx.x + s]);
        __syncthreads();
    }
    if (threadIdx.x == 0) out[0] = 50.0f / red[0];
}

// ---------------------------------------------------------------------------
// GEMM partials: grid 256 = (strip s = bx>>3) x (kslice k = bx&7), 512 thr.
// Block computes P[k*2+kh][s] contributions, kr = [k*512,(k+1)*512).
// Wave w: mh=w&1, nh=(w>>1)&1, kh=w>>2 (256-wide K half). Each wave writes
// its OWN partial slice (k*2+kh) -> no inter-wave aliasing (round-4 bug fix).
// Per iter: 12 coalesced 16B frag loads, 24 MFMAs. No LDS, no barriers.
// ---------------------------------------------------------------------------
__global__ __launch_bounds__(512, 2) void gemm_kernel(
    const unsigned short* __restrict__ gfh,
    const unsigned short* __restrict__ gfl,
    const unsigned short* __restrict__ Wfh,
    const unsigned short* __restrict__ Wfl,
    float* __restrict__ P)
{
    const int tid  = threadIdx.x;
    const int w    = tid >> 6;
    const int lane = tid & 63;
    const int q    = lane >> 4;
    const int l16  = lane & 15;

    const int s = blockIdx.x >> 3;
    const int k = blockIdx.x & 7;

    const int mh = w & 1;
    const int nh = (w >> 1) & 1;
    const int kh = w >> 2;

    f32x4 acc[2][4] = {};

#pragma unroll
    for (int it = 0; it < 8; ++it) {
        const int kc = k * 16 + kh * 8 + it;
        const size_t aBase = ((size_t)kc * 4) * 512 + lane * 8;          // + msub*512
        const size_t bBase = (((size_t)(s * 8) * 128 + kc) * 64 + lane) * 8;  // + nsub*128*512
        bf16x8 ah[2], al[2], bh[4], bl[4];
#pragma unroll
        for (int mi = 0; mi < 2; ++mi) {
            const size_t a = aBase + (size_t)(mh * 2 + mi) * 512;
            ah[mi] = *(const bf16x8*)&gfh[a];
            al[mi] = *(const bf16x8*)&gfl[a];
        }
#pragma unroll
        for (int ni = 0; ni < 4; ++ni) {
            const size_t b = bBase + (size_t)(nh * 4 + ni) * 128 * 512;
            bh[ni] = *(const bf16x8*)&Wfh[b];
            bl[ni] = *(const bf16x8*)&Wfl[b];
        }
#pragma unroll
        for (int mi = 0; mi < 2; ++mi)
#pragma unroll
            for (int ni = 0; ni < 4; ++ni) {
                acc[mi][ni] = __builtin_amdgcn_mfma_f32_16x16x32_bf16(ah[mi], bh[ni], acc[mi][ni], 0, 0, 0);
                acc[mi][ni] = __builtin_amdgcn_mfma_f32_16x16x32_bf16(al[mi], bh[ni], acc[mi][ni], 0, 0, 0);
                acc[mi][ni] = __builtin_amdgcn_mfma_f32_16x16x32_bf16(ah[mi], bl[ni], acc[mi][ni], 0, 0, 0);
            }
    }

    // Partial slice owned by this wave's kh: part = k*2 + kh.
    float* Pb = &P[((size_t)((k * 2 + kh) * NSTRIP + s) * 64) * 128];
#pragma unroll
    for (int mi = 0; mi < 2; ++mi)
#pragma unroll
        for (int ni = 0; ni < 4; ++ni)
#pragma unroll
            for (int rg = 0; rg < 4; ++rg) {
                const int row = mh * 32 + mi * 16 + q * 4 + rg;
                const int col = nh * 64 + ni * 16 + l16;
                Pb[(size_t)row * 128 + col] = acc[mi][ni][rg];
            }
}

// ---------------------------------------------------------------------------
// Epilogue: 128 blocks x 256 thr; thread t -> (m = t>>9, n0 = (t&511)*8).
// Sums 16 partials, applies b/alpha/clip/sigmoid, updates x (plain), writes
// g hi/lo A-fragments for the next step; plain fp32 g on the last step.
// ---------------------------------------------------------------------------
__global__ __launch_bounds__(256) void epi_kernel(
    const float* __restrict__ P,
    float* __restrict__ x,
    unsigned short* __restrict__ gfh_out,
    unsigned short* __restrict__ gfl_out,
    const float* __restrict__ bvec,
    const float* __restrict__ beta,
    const float* __restrict__ tau,
    const float* __restrict__ dt_ptr,
    const float* __restrict__ maxx_ptr,
    float* __restrict__ gout_f32)             // non-null on last step only
{
    const int t  = blockIdx.x * 256 + threadIdx.x;   // 0..32767
    const int m  = t >> 9;
    const int n0 = (t & 511) * 8;
    const int s  = n0 >> 7;

    float sum[8] = {};
#pragma unroll
    for (int k = 0; k < NPART; ++k) {
        const float* p = &P[((size_t)(k * NSTRIP + s) * 64 + m) * 128 + (n0 & 127)];
        float4 p0 = *(const float4*)&p[0];
        float4 p1 = *(const float4*)&p[4];
        sum[0] += p0.x; sum[1] += p0.y; sum[2] += p0.z; sum[3] += p0.w;
        sum[4] += p1.x; sum[5] += p1.y; sum[6] += p1.z; sum[7] += p1.w;
    }

    const float dt = *dt_ptr;
    const float mx = *maxx_ptr;
    float4 b0 = *(const float4*)&bvec[n0], b1 = *(const float4*)&bvec[n0 + 4];
    float4 e0 = *(const float4*)&beta[n0], e1 = *(const float4*)&beta[n0 + 4];
    float4 t0 = *(const float4*)&tau[n0],  t1 = *(const float4*)&tau[n0 + 4];
    float bb[8] = {b0.x, b0.y, b0.z, b0.w, b1.x, b1.y, b1.z, b1.w};
    float be[8] = {e0.x, e0.y, e0.z, e0.w, e1.x, e1.y, e1.z, e1.w};
    float tv[8] = {t0.x, t0.y, t0.z, t0.w, t1.x, t1.y, t1.z, t1.w};

    float* xp = &x[(size_t)m * NN + n0];
    float4 x0 = *(const float4*)&xp[0], x1 = *(const float4*)&xp[4];
    float xo[8] = {x0.x, x0.y, x0.z, x0.w, x1.x, x1.y, x1.z, x1.w};

    float gg[8];
    unsigned short vh[8], vl[8];
#pragma unroll
    for (int j = 0; j < 8; ++j) {
        const float al = dt / tv[j];
        float xn = al * (sum[j] + bb[j]) + (1.0f - al) * xo[j];
        xn = fminf(fmaxf(xn, -mx), mx);
        float g = 1.0f / (1.0f + __expf(-be[j] * xn));
        xo[j] = xn;
        gg[j] = g;
        unsigned short hi = f2bf(g);
        vh[j] = hi;
        vl[j] = f2bf(g - bf2f(hi));
    }
    *(float4*)&xp[0] = {xo[0], xo[1], xo[2], xo[3]};
    *(float4*)&xp[4] = {xo[4], xo[5], xo[6], xo[7]};

    // A-fragment address for (m, kg = n0..n0+7): j spans 0..7 contiguously
    size_t off = (((size_t)(n0 >> 5) * 4 + (m >> 4)) * 64 + ((n0 & 31) >> 3) * 16 + (m & 15)) * 8;
    *(ushort4*)&gfh_out[off]     = {vh[0], vh[1], vh[2], vh[3]};
    *(ushort4*)&gfh_out[off + 4] = {vh[4], vh[5], vh[6], vh[7]};
    *(ushort4*)&gfl_out[off]     = {vl[0], vl[1], vl[2], vl[3]};
    *(ushort4*)&gfl_out[off + 4] = {vl[4], vl[5], vl[6], vl[7]};

    if (gout_f32) {
        *(float4*)&gout_f32[(size_t)m * NN + n0]     = {gg[0], gg[1], gg[2], gg[3]};
        *(float4*)&gout_f32[(size_t)m * NN + n0 + 4] = {gg[4], gg[5], gg[6], gg[7]};
    }
}

// ---------------------------------------------------------------------------
extern "C" void kernel_launch(void* const* d_in, const int* in_sizes, int n_in,
                              void* d_out, int out_size, void* d_ws, size_t ws_size,
                              hipStream_t stream) {
    const float* state_g = (const float*)d_in[0];
    const float* W       = (const float*)d_in[1];
    const float* b       = (const float*)d_in[2];
    const float* beta    = (const float*)d_in[3];
    const float* tau     = (const float*)d_in[4];
    const float* dt      = (const float*)d_in[5];
    float* out = (float*)d_out;

    char* ws = (char*)d_ws;
    const size_t WH = (size_t)KK * NN * 2;    // 32 MB per W-frag array
    const size_t XB = (size_t)MM * NN * 4;    // 1 MB
    const size_t GB = (size_t)MM * NN * 2;    // 512 KB per g-frag array
    const size_t PB = (size_t)NPART * NSTRIP * 64 * 128 * 4;   // 16 MB
    unsigned short* Wfh = (unsigned short*)ws;
    unsigned short* Wfl = (unsigned short*)(ws + WH);
    float*          x   = (float*)(ws + 2 * WH);
    unsigned short* g0h = (unsigned short*)(ws + 2 * WH + XB);
    unsigned short* g0l = (unsigned short*)(ws + 2 * WH + XB + GB);
    unsigned short* g1h = (unsigned short*)(ws + 2 * WH + XB + 2 * GB);
    unsigned short* g1l = (unsigned short*)(ws + 2 * WH + XB + 3 * GB);
    float*          P   = (float*)(ws + 2 * WH + XB + 4 * GB);
    float*          mxp = (float*)(ws + 2 * WH + XB + 4 * GB + PB);

    symm_kernel<<<dim3(64, 64), 256, 0, stream>>>(W, Wfh, Wfl);
    init_kernel<<<(MM * NN) / 256, 256, 0, stream>>>(state_g, beta, x, g0h, g0l);
    maxx_kernel<<<1, 256, 0, stream>>>(beta, mxp);

    unsigned short *gih = g0h, *gil = g0l, *goh = g1h, *gol = g1l;
    for (int st = 0; st < NSTEP; ++st) {
        float* of = (st == NSTEP - 1) ? out : nullptr;
        gemm_kernel<<<NSTRIP * NSLICE, 512, 0, stream>>>(gih, gil, Wfh, Wfl, P);
        epi_kernel<<<128, 256, 0, stream>>>(P, x, goh, gol, b, beta, tau, dt, mxp, of);
        unsigned short* tp;
        tp = gih; gih = goh; goh = tp;
        tp = gil; gil = gol; gol = tp;
    }
}